// Round 16
// baseline (96.479 us; speedup 1.0000x reference)
//
#include <hip/hip_runtime.h>

// Sizes (fixed):
// x: (8,256,64,64) f32 | w_adj: (18,256,1,1) | b_adj: (18)
// w_off: (18,1,3,3) | b_off: (18) | w_def: (256,256,3,3)
// out: (8,256,64,64) f32
//
// Implicit GEMM: out[cout][pix] = sum_{K=tap*256+c} W[cout][K] * col[K][pix]
// M=256, N=32768, K=2304 -> 38.7 GFLOP -> bf16 MFMA.
// Round 16: (a) k_fused 256 blocks x 1024 thr; block = 128px x 256co, wave =
// 32px x 64co (balanced pw=cw -> min A+W traffic) at 16 waves/CU. Halves
// per-CU LDS A-reads vs R15 and halves block count (weight L2 stream).
// (b) k_prep: xchan fused into transpose blocks -> x read ONCE (saves 33MB).
//
// ws layout (bytes):
//   xchan f32 : [0,        2359296)
//   off   f32 : [2359296,  4718592)
//   wfrag bf16: [4718592,  5898240)
//   xT    bf16: [5898240,  22675456)    8n x 4096pix x 256c
// Fallback (ws too small): fp32 path, w_t f32 at [4718592, 7077888).

typedef __attribute__((ext_vector_type(8))) short short8v;
typedef __attribute__((ext_vector_type(4))) float f32x4;

#define NPLANE 4096

__device__ inline unsigned bf16_1(float a) {
    unsigned u = __float_as_uint(a);
    u += 0x7fffu + ((u >> 16) & 1u);
    return u >> 16;
}
__device__ inline unsigned bf16_pair(float a, float b) {
    unsigned ua = __float_as_uint(a); ua += 0x7fffu + ((ua >> 16) & 1u);
    unsigned ub = __float_as_uint(b); ub += 0x7fffu + ((ub >> 16) & 1u);
    return (ua >> 16) | (ub & 0xffff0000u);
}
__device__ inline unsigned cvt_pk(float lo, float hi) {   // HW RNE pack
    unsigned r;
    asm("v_cvt_pk_bf16_f32 %0, %1, %2" : "=v"(r) : "v"(lo), "v"(hi));
    return r;
}
__device__ inline float bl(unsigned u) { return __uint_as_float(u << 16); }
__device__ inline float bh(unsigned u) { return __uint_as_float(u & 0xffff0000u); }

// LDS-only block barrier: retire ds ops (lgkmcnt) but leave global loads
// (vmcnt) in flight across the barrier.
__device__ inline void block_sync_lgkm() {
    asm volatile("s_waitcnt lgkmcnt(0)" ::: "memory");
    __builtin_amdgcn_s_barrier();
    __builtin_amdgcn_sched_barrier(0);
}

// ---------------- fused prep: [xchan+trans] (512) | wfrag (2304) ----------
// Block A (b < 512): n = b&7 (XCD-aligned), pg = b>>3 -> one 64-px row of
// all 256 channels. Reads x ONCE; produces xT (bf16, transposed) AND xchan
// (1x1 conv, split over 4 channel groups of 64).
__global__ __launch_bounds__(256) void k_prep(const float* __restrict__ x,
                                              const float* __restrict__ w_adj,
                                              const float* __restrict__ b_adj,
                                              const float* __restrict__ w_def,
                                              float* __restrict__ xchan,
                                              ushort* __restrict__ wfrag,
                                              ushort* __restrict__ xT) {
    __shared__ unsigned tileU[64][133];     // 34 KB (133: bank-coprime pad)
    __shared__ float    ubuf[5120];         // 20 KB: wsh[256][20] then part
    int b = blockIdx.x;
    int t = threadIdx.x;
    if (b < 512) {
        int n  = b & 7;
        int pg = b >> 3;                    // 0..63 (row group)
        int pl = t & 63, c4 = t >> 6;       // pixel, channel-group (64 ch)
        // wsh[c][o] (padded 20) = w_adj[o*256+c]
        for (int i = t; i < 4608; i += 256) {
            int o = i >> 8, c = i & 255;
            ubuf[c * 20 + o] = w_adj[i];
        }
        __syncthreads();
        const float* xp = x + (((size_t)(n * 256 + c4 * 64)) << 12)
                            + (pg << 6) + pl;
        float acc18[18];
#pragma unroll
        for (int o = 0; o < 18; ++o) acc18[o] = 0.f;
#pragma unroll 4
        for (int i = 0; i < 32; ++i) {
            float f0 = xp[(size_t)(2 * i) << 12];
            float f1 = xp[(size_t)(2 * i + 1) << 12];
            tileU[pl][c4 * 32 + i] = bf16_pair(f0, f1);
            const float* wr = ubuf + (c4 * 64 + 2 * i) * 20;
#pragma unroll
            for (int o = 0; o < 18; ++o)
                acc18[o] = fmaf(f0, wr[o], fmaf(f1, wr[20 + o], acc18[o]));
        }
        __syncthreads();   // all wsh reads done
        // part[g][px][o] (pad 19) aliases ubuf
#pragma unroll
        for (int o = 0; o < 18; ++o)
            ubuf[(c4 * 64 + pl) * 19 + o] = acc18[o];
        __syncthreads();
        // xT write: 64px x 128 uint, coalesced
        unsigned* dst = (unsigned*)xT;
#pragma unroll 8
        for (int i = 0; i < 32; ++i) {
            int idx = i * 256 + t;
            int px = idx >> 7, cu = idx & 127;
            dst[((size_t)((n << 12) + (pg << 6) + px)) * 128 + cu] =
                tileU[px][cu];
        }
        // xchan write: 18 x 64
        for (int idx = t; idx < 1152; idx += 256) {
            int o = idx >> 6, px = idx & 63;
            float s = b_adj[o];
#pragma unroll
            for (int g = 0; g < 4; ++g) s += ubuf[(g * 64 + px) * 19 + o];
            xchan[(((size_t)(n * 18 + o)) << 12) + (pg << 6) + px] = s;
        }
    } else {
        // ---- weight -> MFMA A-fragment layout ----
        int idx = (b - 512) * 256 + t;
        int e     = idx & 7;
        int lane  = (idx >> 3) & 63;
        int ct    = (idx >> 9) & 15;
        int kstep = idx >> 13;
        int cout = ct * 16 + (lane & 15);
        int c    = ((kstep & 7) << 5) + ((lane >> 4) << 3) + e;
        int tap  = kstep >> 3;
        float v = w_def[cout * 2304 + c * 9 + tap];
        wfrag[idx] = (ushort)bf16_1(v);
    }
}

// ---------------- depthwise 3x3 (groups=18), pad=1 ----------------
__global__ __launch_bounds__(256) void k_off(const float* __restrict__ xchan,
                                             const float* __restrict__ w_off,
                                             const float* __restrict__ b_off,
                                             float* __restrict__ off) {
    int idx = blockIdx.x * 256 + threadIdx.x;
    int pix = idx & 4095;
    int w = pix & 63, h = pix >> 6;
    int rest = idx >> 12;
    int oc = rest % 18;
    const float* wp  = w_off + oc * 9;
    const float* src = xchan + (idx & ~4095);
    float acc = b_off[oc];
#pragma unroll
    for (int i = 0; i < 3; ++i) {
        int hh = h - 1 + i;
        if ((unsigned)hh >= 64u) continue;
#pragma unroll
        for (int j = 0; j < 3; ++j) {
            int ww = w - 1 + j;
            if ((unsigned)ww >= 64u) continue;
            acc = fmaf(src[(hh << 6) + ww], wp[i * 3 + j], acc);
        }
    }
    off[idx] = acc;
}

// ---------------- fused sampler + MFMA GEMM, 1024 thr / 16 waves ---------
// grid = 256 (1/CU): n = b&7 (XCD), tq = b>>3 (0..31, 128-px tile).
// GEMM: wave wv: wp = wv>>2 (32-px group), wc = wv&3 (64-co group);
//   acc[2][4] = 32 VGPR. Balanced pw=cw=... A-LDS 32KB/kstep/CU (half R15),
//   weight lines shared by 4 waves (same wc) -> L1.
// Sampling: ksp = t>>9, p7 = (t>>2)&127, cg = t&3 (4 cgs share one 64B line).
// Batch = 2 ksteps, 36 lgkm-only barriers; gathers 2 batches ahead;
// weights ping-pong (bbE even / bbO odd kstep).
__global__ __launch_bounds__(1024) void k_fused(const ushort* __restrict__ xT,
                                                const float* __restrict__ off,
                                                const ushort* __restrict__ wfrag,
                                                float* __restrict__ out) {
    __shared__ __align__(16) ushort colS[2][2][8][64][8];  // 32 KB

    int t = threadIdx.x;
    int wv = t >> 6, lane = t & 63;
    int n  = blockIdx.x & 7;
    int tq = blockIdx.x >> 3;
    int wp = wv >> 2, wc = wv & 3;

    // sampling role
    int ksp = t >> 9;                // kstep parity within batch
    int r_  = t & 511;
    int p7  = r_ >> 2;               // 0..127
    int cg  = r_ & 3;                // 8 channels each
    int sc  = cg << 3;
    int spix = (tq << 7) + p7;
    int sy = spix >> 6, sx = spix & 63;

    const float* offn = off + (((size_t)n * 18) << 12) + spix;
    const ushort* xTn = xT + (((size_t)n) << 12) * 256;

    // swizzled LDS write slot (logical s = (cg<<4)|(p7&15)) in tile p7>>4
    int wtile = p7 >> 4;
    int wslot = (cg << 4) | (((p7 & 15) ^ (cg << 1)) & 15);
    ushort* wp0 = &colS[0][ksp][wtile][wslot][0];
    ushort* wp1 = &colS[1][ksp][wtile][wslot][0];

    float w00, w01, w10, w11;
    unsigned oA, oB, oC, oD;     // element offsets into xTn (include sc)

    auto tap_setup = [&](int tp) {
        float oyv = offn[(size_t)(2 * tp) << 12];
        float oxv = offn[(size_t)(2 * tp + 1) << 12];
        int trow = (tp * 11) >> 5;           // tp/3 for 0..8
        int tcol = tp - trow * 3;
        float py = (float)(sy - 1 + trow) + oyv;
        float px = (float)(sx - 1 + tcol) + oxv;
        float fy = floorf(py), fx = floorf(px);
        int y0 = (int)fy, x0 = (int)fx;
        float wy1 = py - fy, wx1 = px - fx;
        float ay0 = ((unsigned)y0       < 64u) ? 1.f - wy1 : 0.f;
        float ay1 = ((unsigned)(y0 + 1) < 64u) ? wy1 : 0.f;
        float ax0 = ((unsigned)x0       < 64u) ? 1.f - wx1 : 0.f;
        float ax1 = ((unsigned)(x0 + 1) < 64u) ? wx1 : 0.f;
        w00 = ay0 * ax0; w01 = ay0 * ax1; w10 = ay1 * ax0; w11 = ay1 * ax1;
        int yc0 = min(max(y0, 0), 63), yc1 = min(max(y0 + 1, 0), 63);
        int xc0 = min(max(x0, 0), 63), xc1 = min(max(x0 + 1, 0), 63);
        oA = (unsigned)((((yc0 << 6) + xc0) << 8) + sc);
        oB = (unsigned)((((yc0 << 6) + xc1) << 8) + sc);
        oC = (unsigned)((((yc1 << 6) + xc0) << 8) + sc);
        oD = (unsigned)((((yc1 << 6) + xc1) << 8) + sc);
    };

    // gather set: thread's kstep for batch m is 2m+ksp (2-batch prefetch)
    uint4 gA, gB, gC, gD;
    auto issue = [&](int m) {
        unsigned dd = (unsigned)(((2 * m + ksp) & 7) << 5);
        gA = *(const uint4*)(xTn + oA + dd);
        gB = *(const uint4*)(xTn + oB + dd);
        gC = *(const uint4*)(xTn + oC + dd);
        gD = *(const uint4*)(xTn + oD + dd);
    };
    auto interp_to = [&](ushort* wp_) {
        unsigned qa[4] = {gA.x, gA.y, gA.z, gA.w};
        unsigned qb[4] = {gB.x, gB.y, gB.z, gB.w};
        unsigned qc[4] = {gC.x, gC.y, gC.z, gC.w};
        unsigned qd[4] = {gD.x, gD.y, gD.z, gD.w};
        unsigned rr[4];
#pragma unroll
        for (int i = 0; i < 4; ++i) {
            float v0 = w00 * bl(qa[i]) + w01 * bl(qb[i]) +
                       w10 * bl(qc[i]) + w11 * bl(qd[i]);
            float v1 = w00 * bh(qa[i]) + w01 * bh(qb[i]) +
                       w10 * bh(qc[i]) + w11 * bh(qd[i]);
            rr[i] = cvt_pk(v0, v1);
        }
        *(uint4*)wp_ = make_uint4(rr[0], rr[1], rr[2], rr[3]);
    };

    f32x4 acc[2][4] = {};

    short8v bbE[4], bbO[4];      // ping-pong weight sets
    auto loadW = [&](int ks, short8v* dst) {
        const ushort* wb = wfrag + ((size_t)ks * 16 + (wc << 2)) * 512
                                  + (lane << 3);
#pragma unroll
        for (int j = 0; j < 4; ++j)
            dst[j] = *(const short8v*)(wb + (size_t)j * 512);
    };

    // swizzled read slots (logical slot = lane)
    const int rslot = ((lane >> 4) << 4) | ((lane & 15) ^ ((lane >> 4) << 1));

    // ---- prologue: batch 0 (ksteps 0,1) -> buf0; issue batch 1; W(0) ----
    tap_setup(0);
    issue(0);
    interp_to(wp0);
    issue(1);
    loadW(0, bbE);
    block_sync_lgkm();

    // ---- main loop: 36 batches (72 ksteps), 2x unrolled (static ph) ----
    for (int bt2 = 0; bt2 < 18; ++bt2) {
#pragma unroll
        for (int ph = 0; ph < 2; ++ph) {
            const int bt = bt2 * 2 + ph;
            const ushort* rb = &colS[ph][0][0][0][0];
            // (0) even-kstep A-frags: wave's 2 pixtiles (ksp=0 region)
            short8v ae0 = *(const short8v*)(rb + (((wp * 2 + 0) * 64 + rslot) << 3));
            short8v ae1 = *(const short8v*)(rb + (((wp * 2 + 1) * 64 + rslot) << 3));
            // (1) odd-kstep weights early (used mid-batch)
            loadW(2 * bt + 1, bbO);
            // (2) interp gathers (batch bt+1) -> buf[ph^1]
            if (bt + 1 < 36) interp_to(ph ? wp0 : wp1);
            // (3) issue gathers for batch bt+2
            if (bt + 2 < 36) {
                if (((bt + 2) & 3) == 0) tap_setup((bt + 2) >> 2);
                issue(bt + 2);
            }
            // (4a) MFMA even kstep with bbE
#pragma unroll
            for (int j = 0; j < 4; ++j) {
                acc[0][j] = __builtin_amdgcn_mfma_f32_16x16x32_bf16(
                    bbE[j], ae0, acc[0][j], 0, 0, 0);
                acc[1][j] = __builtin_amdgcn_mfma_f32_16x16x32_bf16(
                    bbE[j], ae1, acc[1][j], 0, 0, 0);
            }
            // (4b) next batch's even weights (bbE consumed above)
            if (bt + 1 < 36) loadW(2 * bt + 2, bbE);
            // (4c) odd-kstep A-frags + MFMA with bbO
            short8v ao0 = *(const short8v*)(rb + (((8 + wp * 2 + 0) * 64 + rslot) << 3));
            short8v ao1 = *(const short8v*)(rb + (((8 + wp * 2 + 1) * 64 + rslot) << 3));
#pragma unroll
            for (int j = 0; j < 4; ++j) {
                acc[0][j] = __builtin_amdgcn_mfma_f32_16x16x32_bf16(
                    bbO[j], ao0, acc[0][j], 0, 0, 0);
                acc[1][j] = __builtin_amdgcn_mfma_f32_16x16x32_bf16(
                    bbO[j], ao1, acc[1][j], 0, 0, 0);
            }
            // (5) LDS-only barrier: vmem prefetch stays in flight
            block_sync_lgkm();
        }
    }

    // epilogue: D layout col = lane&15 (pix), row = (lane>>4)*4 + r (cout)
    int cl = lane & 15;
    int ch = (lane >> 4) << 2;
    float* outn = out + ((size_t)n << 20);
#pragma unroll
    for (int i = 0; i < 2; ++i) {
        int opix = (tq << 7) + (wp << 5) + (i << 4) + cl;
#pragma unroll
        for (int j = 0; j < 4; ++j) {
            int cout = (((wc << 2) + j) << 4) + ch;
            float* op = outn + ((size_t)cout << 12) + opix;
#pragma unroll
            for (int rr = 0; rr < 4; ++rr) op[(size_t)rr << 12] = acc[i][j][rr];
        }
    }
}

// ================= fallback fp32 path (ws too small) =================
__global__ __launch_bounds__(256) void k_xchan(const float* __restrict__ x,
                                               const float* __restrict__ w_adj,
                                               const float* __restrict__ b_adj,
                                               float* __restrict__ xchan) {
    __shared__ float wsh[256][18];
    __shared__ float part[8][32][19];
    int t = threadIdx.x;
    for (int i = t; i < 18 * 256; i += 256) {
        int o = i >> 8, c = i & 255;
        wsh[c][o] = w_adj[i];
    }
    __syncthreads();
    int n    = blockIdx.x >> 7;
    int pix0 = (blockIdx.x & 127) << 5;
    int p = t & 31, g = t >> 5;
    const float* xp = x + ((size_t)n << 20) + ((size_t)g << 17) + pix0 + p;
    float acc[18];
#pragma unroll
    for (int o = 0; o < 18; ++o) acc[o] = 0.f;
#pragma unroll 4
    for (int ci = 0; ci < 32; ++ci) {
        float xv = xp[(size_t)ci << 12];
        const float* wr = wsh[(g << 5) + ci];
#pragma unroll
        for (int o = 0; o < 18; ++o) acc[o] = fmaf(xv, wr[o], acc[o]);
    }
#pragma unroll
    for (int o = 0; o < 18; ++o) part[g][p][o] = acc[o];
    __syncthreads();
    for (int i = t; i < 576; i += 256) {
        int o = i >> 5, p2 = i & 31;
        float s = b_adj[o];
#pragma unroll
        for (int g2 = 0; g2 < 8; ++g2) s += part[g2][p2][o];
        xchan[((size_t)n * 18 + o) * NPLANE + pix0 + p2] = s;
    }
}

__global__ __launch_bounds__(256) void k_reorder(const float* __restrict__ w_def,
                                                 float* __restrict__ w_t) {
    int idx = blockIdx.x * 256 + threadIdx.x;
    int co = idx & 255;
    int c  = (idx >> 8) & 255;
    int k  = idx >> 16;
    w_t[idx] = w_def[co * 2304 + c * 9 + k];
}

__global__ __launch_bounds__(256) void k_deform(const float* __restrict__ x,
                                                const float* __restrict__ off,
                                                const float* __restrict__ w_t,
                                                float* __restrict__ out) {
    __shared__ float colS[16][64];
    __shared__ float wS[16][128];
    __shared__ int   sy0[64], sx0[64];
    __shared__ float swy[64], swx[64];
    int t   = threadIdx.x;
    int n   = blockIdx.x >> 6;
    int h   = blockIdx.x & 63;
    int co0 = blockIdx.y << 7;
    float acc[4][8];
#pragma unroll
    for (int i = 0; i < 4; ++i)
#pragma unroll
        for (int j = 0; j < 8; ++j) acc[i][j] = 0.f;
    int tp = t & 15, tc = t >> 4;
    int cc_b = t >> 4, p0_b = (t & 15) << 2;
    const float* xn = x + (n << 20);
    for (int k = 0; k < 9; ++k) {
        if (t < 64) {
            const float* offp = off + ((n * 18 + 2 * k) << 12) + (h << 6);
            float oyv = offp[t];
            float oxv = offp[4096 + t];
            float py = (float)(h - 1 + k / 3) + oyv;
            float px = (float)(t - 1 + k % 3) + oxv;
            float fy = floorf(py), fx = floorf(px);
            sy0[t] = (int)fy; sx0[t] = (int)fx;
            swy[t] = py - fy; swx[t] = px - fx;
        }
        for (int c0 = 0; c0 < 256; c0 += 16) {
            __syncthreads();
            const float* base = xn + ((c0 + cc_b) << 12);
#pragma unroll
            for (int u = 0; u < 4; ++u) {
                int p = p0_b + u;
                int y0 = sy0[p], x0 = sx0[p];
                float wy = swy[p], wx = swx[p];
                float v00 = 0.f, v01 = 0.f, v10 = 0.f, v11 = 0.f;
                bool oky0 = (unsigned)y0 < 64u, oky1 = (unsigned)(y0 + 1) < 64u;
                bool okx0 = (unsigned)x0 < 64u, okx1 = (unsigned)(x0 + 1) < 64u;
                int r0 = (y0 << 6) + x0;
                if (oky0 && okx0) v00 = base[r0];
                if (oky0 && okx1) v01 = base[r0 + 1];
                if (oky1 && okx0) v10 = base[r0 + 64];
                if (oky1 && okx1) v11 = base[r0 + 65];
                colS[cc_b][p] = (v00 * (1.f - wx) + v01 * wx) * (1.f - wy) +
                                (v10 * (1.f - wx) + v11 * wx) * wy;
            }
            const float* wt = w_t + (k << 16) + (c0 << 8) + co0;
#pragma unroll
            for (int i = 0; i < 2; ++i) {
                int fi = i * 256 + t;
                int cc = fi >> 5;
                int cf = (fi & 31) << 2;
                *(float4*)&wS[cc][cf] = *(const float4*)&wt[(cc << 8) + cf];
            }
            __syncthreads();
#pragma unroll
            for (int kk = 0; kk < 16; ++kk) {
                float4 cv = *(const float4*)&colS[kk][tp << 2];
                float4 w0 = *(const float4*)&wS[kk][tc << 3];
                float4 w1 = *(const float4*)&wS[kk][(tc << 3) + 4];
                float cva[4] = {cv.x, cv.y, cv.z, cv.w};
                float wa[8]  = {w0.x, w0.y, w0.z, w0.w, w1.x, w1.y, w1.z, w1.w};
#pragma unroll
                for (int i = 0; i < 4; ++i)
#pragma unroll
                    for (int j = 0; j < 8; ++j)
                        acc[i][j] = fmaf(cva[i], wa[j], acc[i][j]);
            }
        }
    }
    int ob = (n << 20) + ((co0 + (tc << 3)) << 12) + (h << 6) + (tp << 2);
#pragma unroll
    for (int j = 0; j < 8; ++j) {
        float4 v = {acc[0][j], acc[1][j], acc[2][j], acc[3][j]};
        *(float4*)&out[ob + (j << 12)] = v;
    }
}

extern "C" void kernel_launch(void* const* d_in, const int* in_sizes, int n_in,
                              void* d_out, int out_size, void* d_ws, size_t ws_size,
                              hipStream_t stream) {
    const float* x     = (const float*)d_in[0];
    const float* w_adj = (const float*)d_in[1];
    const float* b_adj = (const float*)d_in[2];
    const float* w_off = (const float*)d_in[3];
    const float* b_off = (const float*)d_in[4];
    const float* w_def = (const float*)d_in[5];
    float* out = (float*)d_out;

    char* ws = (char*)d_ws;
    float* xchan = (float*)ws;                          // 2359296 B
    float* off   = (float*)(ws + 2359296);              // 2359296 B

    const size_t NEED = 22675456;
    if (ws_size >= NEED) {
        ushort* wfrag = (ushort*)(ws + 4718592);        // 1179648 B
        ushort* xT    = (ushort*)(ws + 5898240);        // 16777216 B
        k_prep<<<2816, 256, 0, stream>>>(x, w_adj, b_adj, w_def,
                                         xchan, wfrag, xT);
        k_off<<<2304, 256, 0, stream>>>(xchan, w_off, b_off, off);
        k_fused<<<256, 1024, 0, stream>>>(xT, off, wfrag, out);
    } else {
        float* w_t = (float*)(ws + 4718592);
        k_xchan<<<1024, 256, 0, stream>>>(x, w_adj, b_adj, xchan);
        k_off<<<2304, 256, 0, stream>>>(xchan, w_off, b_off, off);
        k_reorder<<<2304, 256, 0, stream>>>(w_def, w_t);
        k_deform<<<dim3(512, 2), 256, 0, stream>>>(x, off, w_t, out);
    }
}

// Round 17
// 83.665 us; speedup vs baseline: 1.1532x; 1.1532x over previous
//
#include <hip/hip_runtime.h>

// Sizes (fixed):
// x: (8,256,64,64) f32 | w_adj: (18,256,1,1) | b_adj: (18)
// w_off: (18,1,3,3) | b_off: (18) | w_def: (256,256,3,3)
// out: (8,256,64,64) f32
//
// Implicit GEMM: out[cout][pix] = sum_{K=tap*256+c} W[cout][K] * col[K][pix]
// M=256, N=32768, K=2304 -> 38.7 GFLOP -> bf16 MFMA.
// Round 17: recomposition of measured bests. k_fused = R15 exact (512 blk x
// 512 thr, 60.5us measured; R16's 1024-thr monolith regressed to 80.6).
// k_prep = R16's fused xchan+trans (x read once; non-fused time 23.4->15.9us).
//
// ws layout (bytes):
//   xchan f32 : [0,        2359296)
//   off   f32 : [2359296,  4718592)
//   wfrag bf16: [4718592,  5898240)
//   xT    bf16: [5898240,  22675456)    8n x 4096pix x 256c
// Fallback (ws too small): fp32 path, w_t f32 at [4718592, 7077888).

typedef __attribute__((ext_vector_type(8))) short short8v;
typedef __attribute__((ext_vector_type(4))) float f32x4;

#define NPLANE 4096

__device__ inline unsigned bf16_1(float a) {
    unsigned u = __float_as_uint(a);
    u += 0x7fffu + ((u >> 16) & 1u);
    return u >> 16;
}
__device__ inline unsigned bf16_pair(float a, float b) {
    unsigned ua = __float_as_uint(a); ua += 0x7fffu + ((ua >> 16) & 1u);
    unsigned ub = __float_as_uint(b); ub += 0x7fffu + ((ub >> 16) & 1u);
    return (ua >> 16) | (ub & 0xffff0000u);
}
__device__ inline unsigned cvt_pk(float lo, float hi) {   // HW RNE pack
    unsigned r;
    asm("v_cvt_pk_bf16_f32 %0, %1, %2" : "=v"(r) : "v"(lo), "v"(hi));
    return r;
}
__device__ inline float bl(unsigned u) { return __uint_as_float(u << 16); }
__device__ inline float bh(unsigned u) { return __uint_as_float(u & 0xffff0000u); }

// LDS-only block barrier: retire ds ops (lgkmcnt) but leave global loads
// (vmcnt) in flight across the barrier.
__device__ inline void block_sync_lgkm() {
    asm volatile("s_waitcnt lgkmcnt(0)" ::: "memory");
    __builtin_amdgcn_s_barrier();
    __builtin_amdgcn_sched_barrier(0);
}

// ---------------- fused prep: [xchan+trans] (512) | wfrag (2304) ----------
// Block A (b < 512): n = b&7 (XCD-aligned), pg = b>>3 -> one 64-px row of
// all 256 channels. Reads x ONCE; produces xT (bf16, transposed) AND xchan.
__global__ __launch_bounds__(256) void k_prep(const float* __restrict__ x,
                                              const float* __restrict__ w_adj,
                                              const float* __restrict__ b_adj,
                                              const float* __restrict__ w_def,
                                              float* __restrict__ xchan,
                                              ushort* __restrict__ wfrag,
                                              ushort* __restrict__ xT) {
    __shared__ unsigned tileU[64][133];     // 34 KB (133: bank-coprime pad)
    __shared__ float    ubuf[5120];         // 20 KB: wsh[256][20] then part
    int b = blockIdx.x;
    int t = threadIdx.x;
    if (b < 512) {
        int n  = b & 7;
        int pg = b >> 3;                    // 0..63 (row group)
        int pl = t & 63, c4 = t >> 6;       // pixel, channel-group (64 ch)
        for (int i = t; i < 4608; i += 256) {
            int o = i >> 8, c = i & 255;
            ubuf[c * 20 + o] = w_adj[i];
        }
        __syncthreads();
        const float* xp = x + (((size_t)(n * 256 + c4 * 64)) << 12)
                            + (pg << 6) + pl;
        float acc18[18];
#pragma unroll
        for (int o = 0; o < 18; ++o) acc18[o] = 0.f;
#pragma unroll 4
        for (int i = 0; i < 32; ++i) {
            float f0 = xp[(size_t)(2 * i) << 12];
            float f1 = xp[(size_t)(2 * i + 1) << 12];
            tileU[pl][c4 * 32 + i] = bf16_pair(f0, f1);
            const float* wr = ubuf + (c4 * 64 + 2 * i) * 20;
#pragma unroll
            for (int o = 0; o < 18; ++o)
                acc18[o] = fmaf(f0, wr[o], fmaf(f1, wr[20 + o], acc18[o]));
        }
        __syncthreads();   // all wsh reads done
#pragma unroll
        for (int o = 0; o < 18; ++o)
            ubuf[(c4 * 64 + pl) * 19 + o] = acc18[o];
        __syncthreads();
        unsigned* dst = (unsigned*)xT;
#pragma unroll 8
        for (int i = 0; i < 32; ++i) {
            int idx = i * 256 + t;
            int px = idx >> 7, cu = idx & 127;
            dst[((size_t)((n << 12) + (pg << 6) + px)) * 128 + cu] =
                tileU[px][cu];
        }
        for (int idx = t; idx < 1152; idx += 256) {
            int o = idx >> 6, px = idx & 63;
            float s = b_adj[o];
#pragma unroll
            for (int g = 0; g < 4; ++g) s += ubuf[(g * 64 + px) * 19 + o];
            xchan[(((size_t)(n * 18 + o)) << 12) + (pg << 6) + px] = s;
        }
    } else {
        // ---- weight -> MFMA A-fragment layout ----
        int idx = (b - 512) * 256 + t;
        int e     = idx & 7;
        int lane  = (idx >> 3) & 63;
        int ct    = (idx >> 9) & 15;
        int kstep = idx >> 13;
        int cout = ct * 16 + (lane & 15);
        int c    = ((kstep & 7) << 5) + ((lane >> 4) << 3) + e;
        int tap  = kstep >> 3;
        float v = w_def[cout * 2304 + c * 9 + tap];
        wfrag[idx] = (ushort)bf16_1(v);
    }
}

// ---------------- depthwise 3x3 (groups=18), pad=1 ----------------
__global__ __launch_bounds__(256) void k_off(const float* __restrict__ xchan,
                                             const float* __restrict__ w_off,
                                             const float* __restrict__ b_off,
                                             float* __restrict__ off) {
    int idx = blockIdx.x * 256 + threadIdx.x;
    int pix = idx & 4095;
    int w = pix & 63, h = pix >> 6;
    int rest = idx >> 12;
    int oc = rest % 18;
    const float* wp  = w_off + oc * 9;
    const float* src = xchan + (idx & ~4095);
    float acc = b_off[oc];
#pragma unroll
    for (int i = 0; i < 3; ++i) {
        int hh = h - 1 + i;
        if ((unsigned)hh >= 64u) continue;
#pragma unroll
        for (int j = 0; j < 3; ++j) {
            int ww = w - 1 + j;
            if ((unsigned)ww >= 64u) continue;
            acc = fmaf(src[(hh << 6) + ww], wp[i * 3 + j], acc);
        }
    }
    off[idx] = acc;
}

// ---------------- fused sampler + MFMA GEMM, 512 thr / 8 waves (R15) -----
// grid = 512: n = b&7 (XCD), tq = b>>3 (0..63, 64-px tile).
// GEMM: wave wv (0..7) -> couttiles [2wv,2wv+2) x pixtiles 0..3, acc[4][2].
// Sampling: ksp = t>>8, p6 = (t&255)>>2, cg = t&3.
__global__ __launch_bounds__(512) void k_fused(const ushort* __restrict__ xT,
                                               const float* __restrict__ off,
                                               const ushort* __restrict__ wfrag,
                                               float* __restrict__ out) {
    __shared__ __align__(16) ushort colS[2][2][4][64][8];  // 16 KB

    int t = threadIdx.x;
    int wv = t >> 6, lane = t & 63;
    int n  = blockIdx.x & 7;
    int tq = blockIdx.x >> 3;

    // sampling role
    int ksp = t >> 8;                // kstep parity within batch
    int r_  = t & 255;
    int p6  = r_ >> 2;               // 0..63
    int cg  = r_ & 3;                // 8 channels each
    int sc  = cg << 3;
    int spix = (tq << 6) + p6;
    int sy = spix >> 6, sx = spix & 63;

    const float* offn = off + (((size_t)n * 18) << 12) + spix;
    const ushort* xTn = xT + (((size_t)n) << 12) * 256;

    // swizzled LDS write slot (logical s = (cg<<4)|(p6&15)) in tile p6>>4
    int wtile = p6 >> 4;
    int wslot = (cg << 4) | (((p6 & 15) ^ (cg << 1)) & 15);
    ushort* wp0 = &colS[0][ksp][wtile][wslot][0];
    ushort* wp1 = &colS[1][ksp][wtile][wslot][0];

    float w00, w01, w10, w11;
    unsigned oA, oB, oC, oD;     // element offsets into xTn (include sc)

    auto tap_setup = [&](int tp) {
        float oyv = offn[(size_t)(2 * tp) << 12];
        float oxv = offn[(size_t)(2 * tp + 1) << 12];
        int trow = (tp * 11) >> 5;           // tp/3 for 0..8
        int tcol = tp - trow * 3;
        float py = (float)(sy - 1 + trow) + oyv;
        float px = (float)(sx - 1 + tcol) + oxv;
        float fy = floorf(py), fx = floorf(px);
        int y0 = (int)fy, x0 = (int)fx;
        float wy1 = py - fy, wx1 = px - fx;
        float ay0 = ((unsigned)y0       < 64u) ? 1.f - wy1 : 0.f;
        float ay1 = ((unsigned)(y0 + 1) < 64u) ? wy1 : 0.f;
        float ax0 = ((unsigned)x0       < 64u) ? 1.f - wx1 : 0.f;
        float ax1 = ((unsigned)(x0 + 1) < 64u) ? wx1 : 0.f;
        w00 = ay0 * ax0; w01 = ay0 * ax1; w10 = ay1 * ax0; w11 = ay1 * ax1;
        int yc0 = min(max(y0, 0), 63), yc1 = min(max(y0 + 1, 0), 63);
        int xc0 = min(max(x0, 0), 63), xc1 = min(max(x0 + 1, 0), 63);
        oA = (unsigned)((((yc0 << 6) + xc0) << 8) + sc);
        oB = (unsigned)((((yc0 << 6) + xc1) << 8) + sc);
        oC = (unsigned)((((yc1 << 6) + xc0) << 8) + sc);
        oD = (unsigned)((((yc1 << 6) + xc1) << 8) + sc);
    };

    // gather set: thread's kstep for batch m is 2m+ksp (2-batch prefetch)
    uint4 gA, gB, gC, gD;
    auto issue = [&](int m) {
        unsigned dd = (unsigned)(((2 * m + ksp) & 7) << 5);
        gA = *(const uint4*)(xTn + oA + dd);
        gB = *(const uint4*)(xTn + oB + dd);
        gC = *(const uint4*)(xTn + oC + dd);
        gD = *(const uint4*)(xTn + oD + dd);
    };
    auto interp_to = [&](ushort* wp) {
        unsigned qa[4] = {gA.x, gA.y, gA.z, gA.w};
        unsigned qb[4] = {gB.x, gB.y, gB.z, gB.w};
        unsigned qc[4] = {gC.x, gC.y, gC.z, gC.w};
        unsigned qd[4] = {gD.x, gD.y, gD.z, gD.w};
        unsigned rr[4];
#pragma unroll
        for (int i = 0; i < 4; ++i) {
            float v0 = w00 * bl(qa[i]) + w01 * bl(qb[i]) +
                       w10 * bl(qc[i]) + w11 * bl(qd[i]);
            float v1 = w00 * bh(qa[i]) + w01 * bh(qb[i]) +
                       w10 * bh(qc[i]) + w11 * bh(qd[i]);
            rr[i] = cvt_pk(v0, v1);
        }
        *(uint4*)wp = make_uint4(rr[0], rr[1], rr[2], rr[3]);
    };

    f32x4 acc[4][2] = {};
    const int ctb = wv << 1;     // wave's base couttile (2 tiles)

    short8v bbA[2], bbB[2], bbN[2];
    auto loadW = [&](int ks, short8v* dst) {
        const ushort* wb = wfrag + ((size_t)ks * 16 + ctb) * 512 + (lane << 3);
#pragma unroll
        for (int j = 0; j < 2; ++j)
            dst[j] = *(const short8v*)(wb + (size_t)j * 512);
    };

    // swizzled read slots (logical slot = lane)
    const int rslot = ((lane >> 4) << 4) | ((lane & 15) ^ ((lane >> 4) << 1));

    // ---- prologue: batch 0 (ksteps 0,1) -> buf0; issue batch 1; W(0) ----
    tap_setup(0);
    issue(0);
    interp_to(wp0);
    issue(1);
    loadW(0, bbA);
    block_sync_lgkm();

    // ---- main loop: 36 batches (72 ksteps), 2x unrolled (static ph) ----
    for (int bt2 = 0; bt2 < 18; ++bt2) {
#pragma unroll
        for (int ph = 0; ph < 2; ++ph) {
            const int bt = bt2 * 2 + ph;
            const ushort* rb = &colS[ph][0][0][0][0];
            // (0) ds_read even-kstep A-frags (ksp=0 region, 4 tiles)
            short8v ae0 = *(const short8v*)(rb + ((0 * 64 + rslot) << 3));
            short8v ae1 = *(const short8v*)(rb + ((1 * 64 + rslot) << 3));
            short8v ae2 = *(const short8v*)(rb + ((2 * 64 + rslot) << 3));
            short8v ae3 = *(const short8v*)(rb + ((3 * 64 + rslot) << 3));
            // (1) weight loads early (survive barrier; L2 latency hidden)
            loadW(2 * bt + 1, bbB);
            if (bt + 1 < 36) loadW(2 * bt + 2, bbN);
            // (2) interp gathers (batch bt+1) -> buf[ph^1]
            if (bt + 1 < 36) interp_to(ph ? wp0 : wp1);
            // (3) issue gathers for batch bt+2
            if (bt + 2 < 36) {
                if (((bt + 2) & 3) == 0) tap_setup((bt + 2) >> 2);
                issue(bt + 2);
            }
            // (4a) MFMA even kstep (2bt) with bbA
#pragma unroll
            for (int j = 0; j < 2; ++j) {
                acc[0][j] = __builtin_amdgcn_mfma_f32_16x16x32_bf16(
                    bbA[j], ae0, acc[0][j], 0, 0, 0);
                acc[1][j] = __builtin_amdgcn_mfma_f32_16x16x32_bf16(
                    bbA[j], ae1, acc[1][j], 0, 0, 0);
                acc[2][j] = __builtin_amdgcn_mfma_f32_16x16x32_bf16(
                    bbA[j], ae2, acc[2][j], 0, 0, 0);
                acc[3][j] = __builtin_amdgcn_mfma_f32_16x16x32_bf16(
                    bbA[j], ae3, acc[3][j], 0, 0, 0);
            }
            // (4b) odd-kstep A-frags (ksp=1 region) + MFMA with bbB
            short8v ao0 = *(const short8v*)(rb + (((4 + 0) * 64 + rslot) << 3));
            short8v ao1 = *(const short8v*)(rb + (((4 + 1) * 64 + rslot) << 3));
            short8v ao2 = *(const short8v*)(rb + (((4 + 2) * 64 + rslot) << 3));
            short8v ao3 = *(const short8v*)(rb + (((4 + 3) * 64 + rslot) << 3));
#pragma unroll
            for (int j = 0; j < 2; ++j) {
                acc[0][j] = __builtin_amdgcn_mfma_f32_16x16x32_bf16(
                    bbB[j], ao0, acc[0][j], 0, 0, 0);
                acc[1][j] = __builtin_amdgcn_mfma_f32_16x16x32_bf16(
                    bbB[j], ao1, acc[1][j], 0, 0, 0);
                acc[2][j] = __builtin_amdgcn_mfma_f32_16x16x32_bf16(
                    bbB[j], ao2, acc[2][j], 0, 0, 0);
                acc[3][j] = __builtin_amdgcn_mfma_f32_16x16x32_bf16(
                    bbB[j], ao3, acc[3][j], 0, 0, 0);
            }
            // (5) LDS-only barrier
            block_sync_lgkm();
#pragma unroll
            for (int j = 0; j < 2; ++j) bbA[j] = bbN[j];
        }
    }

    // epilogue: D layout col = lane&15 (pix), row = (lane>>4)*4 + r (cout)
    int cl = lane & 15;
    int ch = (lane >> 4) << 2;
    float* outn = out + ((size_t)n << 20);
#pragma unroll
    for (int i = 0; i < 4; ++i) {
        int opix = (tq << 6) + (i << 4) + cl;
#pragma unroll
        for (int j = 0; j < 2; ++j) {
            int cout = ((ctb + j) << 4) + ch;
            float* op = outn + ((size_t)cout << 12) + opix;
#pragma unroll
            for (int rr = 0; rr < 4; ++rr) op[(size_t)rr << 12] = acc[i][j][rr];
        }
    }
}

// ================= fallback fp32 path (ws too small) =================
__global__ __launch_bounds__(256) void k_xchan(const float* __restrict__ x,
                                               const float* __restrict__ w_adj,
                                               const float* __restrict__ b_adj,
                                               float* __restrict__ xchan) {
    __shared__ float wsh[256][18];
    __shared__ float part[8][32][19];
    int t = threadIdx.x;
    for (int i = t; i < 18 * 256; i += 256) {
        int o = i >> 8, c = i & 255;
        wsh[c][o] = w_adj[i];
    }
    __syncthreads();
    int n    = blockIdx.x >> 7;
    int pix0 = (blockIdx.x & 127) << 5;
    int p = t & 31, g = t >> 5;
    const float* xp = x + ((size_t)n << 20) + ((size_t)g << 17) + pix0 + p;
    float acc[18];
#pragma unroll
    for (int o = 0; o < 18; ++o) acc[o] = 0.f;
#pragma unroll 4
    for (int ci = 0; ci < 32; ++ci) {
        float xv = xp[(size_t)ci << 12];
        const float* wr = wsh[(g << 5) + ci];
#pragma unroll
        for (int o = 0; o < 18; ++o) acc[o] = fmaf(xv, wr[o], acc[o]);
    }
#pragma unroll
    for (int o = 0; o < 18; ++o) part[g][p][o] = acc[o];
    __syncthreads();
    for (int i = t; i < 576; i += 256) {
        int o = i >> 5, p2 = i & 31;
        float s = b_adj[o];
#pragma unroll
        for (int g2 = 0; g2 < 8; ++g2) s += part[g2][p2][o];
        xchan[((size_t)n * 18 + o) * NPLANE + pix0 + p2] = s;
    }
}

__global__ __launch_bounds__(256) void k_reorder(const float* __restrict__ w_def,
                                                 float* __restrict__ w_t) {
    int idx = blockIdx.x * 256 + threadIdx.x;
    int co = idx & 255;
    int c  = (idx >> 8) & 255;
    int k  = idx >> 16;
    w_t[idx] = w_def[co * 2304 + c * 9 + k];
}

__global__ __launch_bounds__(256) void k_deform(const float* __restrict__ x,
                                                const float* __restrict__ off,
                                                const float* __restrict__ w_t,
                                                float* __restrict__ out) {
    __shared__ float colS[16][64];
    __shared__ float wS[16][128];
    __shared__ int   sy0[64], sx0[64];
    __shared__ float swy[64], swx[64];
    int t   = threadIdx.x;
    int n   = blockIdx.x >> 6;
    int h   = blockIdx.x & 63;
    int co0 = blockIdx.y << 7;
    float acc[4][8];
#pragma unroll
    for (int i = 0; i < 4; ++i)
#pragma unroll
        for (int j = 0; j < 8; ++j) acc[i][j] = 0.f;
    int tp = t & 15, tc = t >> 4;
    int cc_b = t >> 4, p0_b = (t & 15) << 2;
    const float* xn = x + (n << 20);
    for (int k = 0; k < 9; ++k) {
        if (t < 64) {
            const float* offp = off + ((n * 18 + 2 * k) << 12) + (h << 6);
            float oyv = offp[t];
            float oxv = offp[4096 + t];
            float py = (float)(h - 1 + k / 3) + oyv;
            float px = (float)(t - 1 + k % 3) + oxv;
            float fy = floorf(py), fx = floorf(px);
            sy0[t] = (int)fy; sx0[t] = (int)fx;
            swy[t] = py - fy; swx[t] = px - fx;
        }
        for (int c0 = 0; c0 < 256; c0 += 16) {
            __syncthreads();
            const float* base = xn + ((c0 + cc_b) << 12);
#pragma unroll
            for (int u = 0; u < 4; ++u) {
                int p = p0_b + u;
                int y0 = sy0[p], x0 = sx0[p];
                float wy = swy[p], wx = swx[p];
                float v00 = 0.f, v01 = 0.f, v10 = 0.f, v11 = 0.f;
                bool oky0 = (unsigned)y0 < 64u, oky1 = (unsigned)(y0 + 1) < 64u;
                bool okx0 = (unsigned)x0 < 64u, okx1 = (unsigned)(x0 + 1) < 64u;
                int r0 = (y0 << 6) + x0;
                if (oky0 && okx0) v00 = base[r0];
                if (oky0 && okx1) v01 = base[r0 + 1];
                if (oky1 && okx0) v10 = base[r0 + 64];
                if (oky1 && okx1) v11 = base[r0 + 65];
                colS[cc_b][p] = (v00 * (1.f - wx) + v01 * wx) * (1.f - wy) +
                                (v10 * (1.f - wx) + v11 * wx) * wy;
            }
            const float* wt = w_t + (k << 16) + (c0 << 8) + co0;
#pragma unroll
            for (int i = 0; i < 2; ++i) {
                int fi = i * 256 + t;
                int cc = fi >> 5;
                int cf = (fi & 31) << 2;
                *(float4*)&wS[cc][cf] = *(const float4*)&wt[(cc << 8) + cf];
            }
            __syncthreads();
#pragma unroll
            for (int kk = 0; kk < 16; ++kk) {
                float4 cv = *(const float4*)&colS[kk][tp << 2];
                float4 w0 = *(const float4*)&wS[kk][tc << 3];
                float4 w1 = *(const float4*)&wS[kk][(tc << 3) + 4];
                float cva[4] = {cv.x, cv.y, cv.z, cv.w};
                float wa[8]  = {w0.x, w0.y, w0.z, w0.w, w1.x, w1.y, w1.z, w1.w};
#pragma unroll
                for (int i = 0; i < 4; ++i)
#pragma unroll
                    for (int j = 0; j < 8; ++j)
                        acc[i][j] = fmaf(cva[i], wa[j], acc[i][j]);
            }
        }
    }
    int ob = (n << 20) + ((co0 + (tc << 3)) << 12) + (h << 6) + (tp << 2);
#pragma unroll
    for (int j = 0; j < 8; ++j) {
        float4 v = {acc[0][j], acc[1][j], acc[2][j], acc[3][j]};
        *(float4*)&out[ob + (j << 12)] = v;
    }
}

extern "C" void kernel_launch(void* const* d_in, const int* in_sizes, int n_in,
                              void* d_out, int out_size, void* d_ws, size_t ws_size,
                              hipStream_t stream) {
    const float* x     = (const float*)d_in[0];
    const float* w_adj = (const float*)d_in[1];
    const float* b_adj = (const float*)d_in[2];
    const float* w_off = (const float*)d_in[3];
    const float* b_off = (const float*)d_in[4];
    const float* w_def = (const float*)d_in[5];
    float* out = (float*)d_out;

    char* ws = (char*)d_ws;
    float* xchan = (float*)ws;                          // 2359296 B
    float* off   = (float*)(ws + 2359296);              // 2359296 B

    const size_t NEED = 22675456;
    if (ws_size >= NEED) {
        ushort* wfrag = (ushort*)(ws + 4718592);        // 1179648 B
        ushort* xT    = (ushort*)(ws + 5898240);        // 16777216 B
        k_prep<<<2816, 256, 0, stream>>>(x, w_adj, b_adj, w_def,
                                         xchan, wfrag, xT);
        k_off<<<2304, 256, 0, stream>>>(xchan, w_off, b_off, off);
        k_fused<<<512, 512, 0, stream>>>(xT, off, wfrag, out);
    } else {
        float* w_t = (float*)(ws + 4718592);
        k_xchan<<<1024, 256, 0, stream>>>(x, w_adj, b_adj, xchan);
        k_off<<<2304, 256, 0, stream>>>(xchan, w_off, b_off, off);
        k_reorder<<<2304, 256, 0, stream>>>(w_def, w_t);
        k_deform<<<dim3(512, 2), 256, 0, stream>>>(x, off, w_t, out);
    }
}